// Round 4
// baseline (135.180 us; speedup 1.0000x reference)
//
#include <hip/hip_runtime.h>

typedef __bf16 bf16x8 __attribute__((ext_vector_type(8)));
typedef float  f32x4  __attribute__((ext_vector_type(4)));

__device__ inline unsigned short f32_to_bf16(float f) {
    union { float f; unsigned int u; } v; v.f = f;
    unsigned int lsb = (v.u >> 16) & 1u;
    v.u += 0x7fffu + lsb;                 // round-to-nearest-even
    return (unsigned short)(v.u >> 16);
}

__device__ inline void gload_lds16(const void* g, void* l) {
    __builtin_amdgcn_global_load_lds((const __attribute__((address_space(1))) void*)g,
                                     (__attribute__((address_space(3))) void*)l,
                                     16, 0, 0);
}

// ---- pass 1a: x f32 -> bf16, plus per-row sum of squares (f32, exact) ----
__global__ __launch_bounds__(256) void convert_x_kernel(
        const float* __restrict__ x, unsigned short* __restrict__ x16,
        float* __restrict__ x_sq, int D) {
    const int n = blockIdx.x;
    const int t = threadIdx.x;
    const float* xr = x + (size_t)n * D;
    unsigned short* xo = x16 + (size_t)n * D;
    float acc = 0.f;
    for (int p = 0; p < D / 1024; ++p) {
        const int col = p * 1024 + t * 4;
        float4 v = *(const float4*)(xr + col);
        acc += v.x * v.x + v.y * v.y + v.z * v.z + v.w * v.w;
        ushort4 o;
        o.x = f32_to_bf16(v.x); o.y = f32_to_bf16(v.y);
        o.z = f32_to_bf16(v.z); o.w = f32_to_bf16(v.w);
        *(ushort4*)(xo + col) = o;
    }
    for (int off = 32; off; off >>= 1) acc += __shfl_down(acc, off, 64);
    __shared__ float sbuf[4];
    if ((t & 63) == 0) sbuf[t >> 6] = acc;
    __syncthreads();
    if (t == 0) x_sq[n] = sbuf[0] + sbuf[1] + sbuf[2] + sbuf[3];
}

// ---- pass 1b: mu f32 -> bf16 (zero-padded to Cpad rows), plus mu_sq ----
__global__ __launch_bounds__(256) void convert_mu_kernel(
        const float* __restrict__ mu, unsigned short* __restrict__ mu16,
        float* __restrict__ mu_sq, int D, int C) {
    const int c = blockIdx.x;
    const int t = threadIdx.x;
    unsigned short* mo = mu16 + (size_t)c * D;
    if (c >= C) {
        for (int p = 0; p < D / 1024; ++p) {
            const int col = p * 1024 + t * 4;
            *(ushort4*)(mo + col) = make_ushort4(0, 0, 0, 0);
        }
        if (t == 0) mu_sq[c] = 0.f;
        return;
    }
    const float* mr = mu + (size_t)c * D;
    float acc = 0.f;
    for (int p = 0; p < D / 1024; ++p) {
        const int col = p * 1024 + t * 4;
        float4 v = *(const float4*)(mr + col);
        acc += v.x * v.x + v.y * v.y + v.z * v.z + v.w * v.w;
        ushort4 o;
        o.x = f32_to_bf16(v.x); o.y = f32_to_bf16(v.y);
        o.z = f32_to_bf16(v.z); o.w = f32_to_bf16(v.w);
        *(ushort4*)(mo + col) = o;
    }
    for (int off = 32; off; off >>= 1) acc += __shfl_down(acc, off, 64);
    __shared__ float sbuf[4];
    if ((t & 63) == 0) sbuf[t >> 6] = acc;
    __syncthreads();
    if (t == 0) mu_sq[c] = sbuf[0] + sbuf[1] + sbuf[2] + sbuf[3];
}

// ---- pass 2: 256x128 tile, BK=32, 3-buffer LDS, 2 blocks/CU, fused LSE ----
// LDS per buffer (24KB): A [256 rows][64B] @0, B [128 rows][64B] @16K
// swizzle: slot (row, kc) holds global chunk kc ^ ((row>>1)&3)  (involution)
#define BM 256
#define BN 128
#define BK 32
#define BUFB 24576

__global__ __launch_bounds__(256, 2) void gemm_fused_kernel(
        const unsigned short* __restrict__ A,   // [M][K] bf16
        const unsigned short* __restrict__ B,   // [Cpad][K] bf16
        const float* __restrict__ x_sq, const float* __restrict__ mu_sq,
        const int* __restrict__ y,
        float* __restrict__ pM, float* __restrict__ pS, float* __restrict__ pP,
        int K, int C, int NCB) {
    __shared__ __align__(16) char smem[3 * BUFB];   // 72KB -> 2 blocks/CU

    const int t  = threadIdx.x;
    const int l  = t & 63, w = t >> 6;
    const int wr = w >> 1, wc = w & 1;              // 2M x 2N wave grid
    const int lr = l & 15, kh = l >> 4;
    const int rowBase = blockIdx.x * BM;
    const int colBase = blockIdx.y * BN;
    const int nt = K / BK;                          // 64 K-tiles

    // ---- staging: linear LDS dest, pre-swizzled global source ----
    const int srow = w * 16 + (l >> 2);             // +64 per round r
    const int kc_src = (l & 3) ^ ((l >> 3) & 3);    // chunk slot (l&3) holds this
    const unsigned short* gA = A + (size_t)(rowBase + srow) * K + kc_src * 8;
    const unsigned short* gB = B + (size_t)(colBase + srow) * K + kc_src * 8;

    auto STAGE = [&](int q) {
        const int qc = (q < nt) ? q : nt - 1;       // tail: rewrites identical bytes
        char* base = smem + (q % 3) * BUFB;
        const size_t ko = (size_t)qc * BK;
#pragma unroll
        for (int r = 0; r < 4; ++r)
            gload_lds16(gA + ko + (size_t)r * 64 * K, base + r * 4096 + t * 16);
#pragma unroll
        for (int r = 0; r < 2; ++r)
            gload_lds16(gB + ko + (size_t)r * 64 * K, base + 16384 + r * 4096 + t * 16);
    };

    // ---- read side (swizzled, conflict-free) ----
    const int chA = ((kh ^ ((lr >> 1) & 3)) << 4);

    f32x4 acc[8][4];
#pragma unroll
    for (int m = 0; m < 8; ++m)
#pragma unroll
        for (int n = 0; n < 4; ++n) acc[m][n] = (f32x4){0.f, 0.f, 0.f, 0.f};

    STAGE(0); STAGE(1);
    asm volatile("s_waitcnt vmcnt(6)" ::: "memory");   // tile 0 resident
    __builtin_amdgcn_s_barrier();

    int rb = 0;
#pragma unroll 1
    for (int tt = 0; tt < nt; ++tt) {
        STAGE(tt + 2);                              // depth-2 prefetch (other buffer)
        const char* bufA = smem + rb * BUFB;
        bf16x8 af[8], bf[4];
#pragma unroll
        for (int m = 0; m < 8; ++m)
            af[m] = *(const bf16x8*)(bufA + (wr * 128 + m * 16 + lr) * 64 + chA);
#pragma unroll
        for (int n = 0; n < 4; ++n)
            bf[n] = *(const bf16x8*)(bufA + 16384 + (wc * 64 + n * 16 + lr) * 64 + chA);
        asm volatile("s_waitcnt lgkmcnt(0)" ::: "memory");
        __builtin_amdgcn_s_setprio(1);
#pragma unroll
        for (int m = 0; m < 8; ++m)
#pragma unroll
            for (int n = 0; n < 4; ++n)
                acc[m][n] = __builtin_amdgcn_mfma_f32_16x16x32_bf16(af[m], bf[n], acc[m][n], 0, 0, 0);
        __builtin_amdgcn_s_setprio(0);
        asm volatile("s_waitcnt vmcnt(6)" ::: "memory");  // tile tt+1 resident; tt+2 in flight
        __builtin_amdgcn_s_barrier();
        rb = rb + 1; if (rb == 3) rb = 0;
    }

    // ---- fused epilogue: per-(row, colblock) LSE partials; alias smem ----
    __syncthreads();
    float (*part)[2][3] = (float(*)[2][3])smem;     // [256 rows][2 wc][max,sum,pick]

    // C/D layout: col = lane&15 (lr), row = kh*4 + reg j
#pragma unroll
    for (int m = 0; m < 8; ++m) {
#pragma unroll
        for (int j = 0; j < 4; ++j) {
            const int row_l = wr * 128 + m * 16 + kh * 4 + j;
            const int grow = rowBase + row_l;
            const float xs = x_sq[grow];
            const int yr = y[grow];
            float v[4];
            float vmax = -3.4e38f, pick = -1.f;
#pragma unroll
            for (int n = 0; n < 4; ++n) {
                const int col = colBase + wc * 64 + n * 16 + lr;
                const float cr = acc[m][n][j];
                const float sq = fmaxf(xs - 2.f * cr + mu_sq[col], 0.f) * 0.5f;
                const float d = sqrtf(sq);
                const float adj = (col == yr) ? 1.5f * d : d;
                if (col == yr) pick = adj;
                v[n] = (col < C) ? -adj : -1e30f;
                vmax = fmaxf(vmax, v[n]);
            }
            for (int off = 1; off <= 8; off <<= 1)
                vmax = fmaxf(vmax, __shfl_xor(vmax, off, 64));
            float s = 0.f;
#pragma unroll
            for (int n = 0; n < 4; ++n) s += expf(v[n] - vmax);
            for (int off = 1; off <= 8; off <<= 1) s += __shfl_xor(s, off, 64);
            for (int off = 1; off <= 8; off <<= 1)
                pick = fmaxf(pick, __shfl_xor(pick, off, 64));
            if (lr == 0) {
                part[row_l][wc][0] = vmax;
                part[row_l][wc][1] = s;
                part[row_l][wc][2] = pick;
            }
        }
    }
    __syncthreads();
    {
        float Mx = fmaxf(part[t][0][0], part[t][1][0]);
        float S = part[t][0][1] * expf(part[t][0][0] - Mx)
                + part[t][1][1] * expf(part[t][1][0] - Mx);
        float pk = fmaxf(part[t][0][2], part[t][1][2]);
        const size_t o = (size_t)(rowBase + t) * NCB + blockIdx.y;
        pM[o] = Mx; pS[o] = S; pP[o] = pk;
    }
}

// ---- pass 3: merge colblock partials -> per-row loss -> per-block sum ----
__global__ __launch_bounds__(256) void loss_combine_kernel(
        const float* __restrict__ pM, const float* __restrict__ pS,
        const float* __restrict__ pP, float* __restrict__ bsum, int NCB) {
    const int t = threadIdx.x;
    const int row = blockIdx.x * 256 + t;
    float Mx = -3.4e38f;
    for (int b = 0; b < NCB; ++b) Mx = fmaxf(Mx, pM[(size_t)row * NCB + b]);
    float S = 0.f, pick = -1.f;
    for (int b = 0; b < NCB; ++b) {
        S += pS[(size_t)row * NCB + b] * expf(pM[(size_t)row * NCB + b] - Mx);
        pick = fmaxf(pick, pP[(size_t)row * NCB + b]);
    }
    float loss = pick + logf(S) + Mx;
    for (int off = 32; off; off >>= 1) loss += __shfl_down(loss, off, 64);
    __shared__ float sb[4];
    if ((t & 63) == 0) sb[t >> 6] = loss;
    __syncthreads();
    if (t == 0) bsum[blockIdx.x] = sb[0] + sb[1] + sb[2] + sb[3];
}

__global__ __launch_bounds__(64) void final_mean_kernel(
        const float* __restrict__ bsum, float* __restrict__ out, int nb, int N) {
    float a = 0.f;
    for (int i = threadIdx.x; i < nb; i += 64) a += bsum[i];
    for (int off = 32; off; off >>= 1) a += __shfl_down(a, off, 64);
    if (threadIdx.x == 0) out[0] = a / (float)N;
}

extern "C" void kernel_launch(void* const* d_in, const int* in_sizes, int n_in,
                              void* d_out, int out_size, void* d_ws, size_t ws_size,
                              hipStream_t stream) {
    const float* x  = (const float*)d_in[0];
    const int*   y  = (const int*)d_in[1];
    const float* mu = (const float*)d_in[2];

    const int N = in_sizes[1];                 // 16384
    const int D = in_sizes[0] / N;             // 2048
    const int C = in_sizes[2] / D;             // 1000
    const int Cpad = ((C + 127) / 128) * 128;  // 1024
    const int NCB = Cpad / BN;                 // 8 column blocks
    const int NRB = N / 256;                   // 64 row blocks

    char* ws = (char*)d_ws;
    unsigned short* x16  = (unsigned short*)ws; ws += (size_t)N * D * 2;      // 67.1 MB
    unsigned short* mu16 = (unsigned short*)ws; ws += (size_t)Cpad * D * 2;   //  4.2 MB
    float* x_sq  = (float*)ws;                  ws += (size_t)N * 4;
    float* mu_sq = (float*)ws;                  ws += (size_t)Cpad * 4;
    float* pM    = (float*)ws;                  ws += (size_t)N * NCB * 4;
    float* pS    = (float*)ws;                  ws += (size_t)N * NCB * 4;
    float* pP    = (float*)ws;                  ws += (size_t)N * NCB * 4;
    float* bsum  = (float*)ws;                  ws += (size_t)NRB * 4;

    convert_x_kernel<<<N, 256, 0, stream>>>(x, x16, x_sq, D);
    convert_mu_kernel<<<Cpad, 256, 0, stream>>>(mu, mu16, mu_sq, D, C);
    gemm_fused_kernel<<<dim3(N / BM, Cpad / BN), 256, 0, stream>>>(
        x16, mu16, x_sq, mu_sq, y, pM, pS, pP, D, C, NCB);
    loss_combine_kernel<<<NRB, 256, 0, stream>>>(pM, pS, pP, bsum, NCB);
    final_mean_kernel<<<1, 64, 0, stream>>>(bsum, d_out ? (float*)d_out : nullptr, NRB, N);
}

// Round 5
// 118.616 us; speedup vs baseline: 1.1396x; 1.1396x over previous
//
#include <hip/hip_runtime.h>

typedef __bf16 bf16x8 __attribute__((ext_vector_type(8)));
typedef float  f32x4  __attribute__((ext_vector_type(4)));

__device__ inline unsigned short f32_to_bf16(float f) {
    union { float f; unsigned int u; } v; v.f = f;
    unsigned int lsb = (v.u >> 16) & 1u;
    v.u += 0x7fffu + lsb;                 // round-to-nearest-even
    return (unsigned short)(v.u >> 16);
}

__device__ inline void gload_lds16(const void* g, void* l) {
    __builtin_amdgcn_global_load_lds((const __attribute__((address_space(1))) void*)g,
                                     (__attribute__((address_space(3))) void*)l,
                                     16, 0, 0);
}

// ---- pass 1a: x f32 -> bf16, plus per-row sum of squares (f32, exact) ----
__global__ __launch_bounds__(256) void convert_x_kernel(
        const float* __restrict__ x, unsigned short* __restrict__ x16,
        float* __restrict__ x_sq, int D) {
    const int n = blockIdx.x;
    const int t = threadIdx.x;
    const float* xr = x + (size_t)n * D;
    unsigned short* xo = x16 + (size_t)n * D;
    float acc = 0.f;
    for (int p = 0; p < D / 1024; ++p) {
        const int col = p * 1024 + t * 4;
        float4 v = *(const float4*)(xr + col);
        acc += v.x * v.x + v.y * v.y + v.z * v.z + v.w * v.w;
        ushort4 o;
        o.x = f32_to_bf16(v.x); o.y = f32_to_bf16(v.y);
        o.z = f32_to_bf16(v.z); o.w = f32_to_bf16(v.w);
        *(ushort4*)(xo + col) = o;
    }
    for (int off = 32; off; off >>= 1) acc += __shfl_down(acc, off, 64);
    __shared__ float sbuf[4];
    if ((t & 63) == 0) sbuf[t >> 6] = acc;
    __syncthreads();
    if (t == 0) x_sq[n] = sbuf[0] + sbuf[1] + sbuf[2] + sbuf[3];
}

// ---- pass 1b: mu f32 -> bf16 (zero-padded to Cpad rows), plus mu_sq ----
__global__ __launch_bounds__(256) void convert_mu_kernel(
        const float* __restrict__ mu, unsigned short* __restrict__ mu16,
        float* __restrict__ mu_sq, int D, int C) {
    const int c = blockIdx.x;
    const int t = threadIdx.x;
    unsigned short* mo = mu16 + (size_t)c * D;
    if (c >= C) {
        for (int p = 0; p < D / 1024; ++p) {
            const int col = p * 1024 + t * 4;
            *(ushort4*)(mo + col) = make_ushort4(0, 0, 0, 0);
        }
        if (t == 0) mu_sq[c] = 0.f;
        return;
    }
    const float* mr = mu + (size_t)c * D;
    float acc = 0.f;
    for (int p = 0; p < D / 1024; ++p) {
        const int col = p * 1024 + t * 4;
        float4 v = *(const float4*)(mr + col);
        acc += v.x * v.x + v.y * v.y + v.z * v.z + v.w * v.w;
        ushort4 o;
        o.x = f32_to_bf16(v.x); o.y = f32_to_bf16(v.y);
        o.z = f32_to_bf16(v.z); o.w = f32_to_bf16(v.w);
        *(ushort4*)(mo + col) = o;
    }
    for (int off = 32; off; off >>= 1) acc += __shfl_down(acc, off, 64);
    __shared__ float sbuf[4];
    if ((t & 63) == 0) sbuf[t >> 6] = acc;
    __syncthreads();
    if (t == 0) mu_sq[c] = sbuf[0] + sbuf[1] + sbuf[2] + sbuf[3];
}

// ---- pass 2: m201-template 256x256x64 GEMM, st_16x32 LDS, fused partial-LSE ----
// LDS dbuf d (64KB @ d*65536): A-h0 @0, A-h1 @16K, B-h0 @32K, B-h1 @48K.
// Each 16KB half = 8x2 subtiles (16 rows x 32 bf16 = 1024B), subtile-major;
// within-subtile byte ^= ((byte>>9)&1)<<5  (st_16x32).
#define BM 256
#define BN 256
#define BK 64

__global__ __launch_bounds__(512, 2) void gemm_fused_kernel(
        const unsigned short* __restrict__ A,   // [M][K] bf16
        const unsigned short* __restrict__ B,   // [Cpad][K] bf16
        const float* __restrict__ x_sq, const float* __restrict__ mu_sq,
        const int* __restrict__ y,
        float* __restrict__ pM, float* __restrict__ pS, float* __restrict__ pP,
        int K, int C, int NCB) {
    __shared__ __align__(16) char smem[131072];

    const int t  = threadIdx.x;
    const int l  = t & 63, w = t >> 6;
    const int wr = w >> 2, wc = w & 3;            // 2M x 4N waves, 128x64 each
    const int lr = l & 15, kh = l >> 4;
    const int rowBase = blockIdx.x * BM;
    const int colBase = blockIdx.y * BN;
    const int nt = K / BK;                        // 32 K-tiles

    // ---- staging: linear LDS dest (t*16), source pre-swizzled (involution) ----
    const int u    = t ^ ((t & 32) >> 4);         // dest-swizzle preimage
    const int sub0 = u >> 6;                      // subtile idx for load 0
    const int row0 = (sub0 >> 1) * 16 + ((u >> 2) & 15);
    const int kc0  = (sub0 & 1) * 4 + (u & 3);    // 16B k-chunk (8 bf16)
    const unsigned short* aSrc = A + (size_t)(rowBase + row0) * K + kc0 * 8;
    const unsigned short* bSrc = B + (size_t)(colBase + row0) * K + kc0 * 8;

    auto STAGE = [&](int q2, int part) {          // part: 0 A-h0, 1 A-h1, 2 B-h0, 3 B-h1
        const int qc = (q2 < nt) ? q2 : nt - 1;   // tail: harmless rewrites
        char* dst = smem + (q2 & 1) * 65536 + (part >> 1) * 32768
                         + (part & 1) * 16384 + t * 16;
        const unsigned short* g = ((part >> 1) ? bSrc : aSrc)
                                + (size_t)(part & 1) * 128 * K + (size_t)qc * BK;
        gload_lds16(g, dst);
        gload_lds16(g + (size_t)64 * K, dst + 8192);   // rows +64
    };

    // ---- read side: frag (Rsub, ks) at ((Rsub*2+ks)<<10) + lrkh  (conflict-free) ----
    const int lrkh = lr * 64 + ((kh * 16) ^ ((lr & 8) << 2));
    const char* aHalf = smem + wr * 16384 + lrkh;
    const char* bHalf = smem + 32768 + (wc >> 1) * 16384 + ((wc & 1) << 12) + lrkh;
    // A frag mf (0..7), ks: aHalf + d + ((mf*2+ks)<<10)
    // B frag nf (0..3), ks: bHalf + d + ((nf*2+ks)<<10)   ((wc&1)*4 folded into base)

    f32x4 acc[8][4];
#pragma unroll
    for (int m = 0; m < 8; ++m)
#pragma unroll
        for (int n = 0; n < 4; ++n) acc[m][n] = (f32x4){0.f, 0.f, 0.f, 0.f};

    // prologue: tile0 all 4 halves, tile1 A-halves (B of tile1 staged in q0 Ph1/2)
    STAGE(0, 0); STAGE(0, 1); STAGE(0, 2); STAGE(0, 3);
    STAGE(1, 0); STAGE(1, 1);
    asm volatile("s_waitcnt vmcnt(4)" ::: "memory");   // tile0 resident
    __builtin_amdgcn_s_barrier();

    bf16x8 aF[8][2], b0[2][2], b1[2][2];

#define MFMA_Q(MOFF, BREG)                                                        \
    do {                                                                          \
        _Pragma("unroll")                                                         \
        for (int m = 0; m < 4; ++m)                                               \
            _Pragma("unroll")                                                     \
            for (int n = 0; n < 2; ++n) {                                         \
                f32x4* a_ = &acc[(MOFF) + m][(BREG == b1 ? 2 : 0) + n];           \
                *a_ = __builtin_amdgcn_mfma_f32_16x16x32_bf16(                    \
                    aF[(MOFF) + m][0], BREG[n][0], *a_, 0, 0, 0);                 \
                *a_ = __builtin_amdgcn_mfma_f32_16x16x32_bf16(                    \
                    aF[(MOFF) + m][1], BREG[n][1], *a_, 0, 0, 0);                 \
            }                                                                     \
    } while (0)

#pragma unroll 1
    for (int q = 0; q < nt; ++q) {
        const int d = (q & 1) * 65536;
        // -- Phase 1: read A-mh0 + B-nh0; stage B-h0(q+1); MFMA (mh0, nh0)
#pragma unroll
        for (int m = 0; m < 4; ++m) {
            aF[m][0] = *(const bf16x8*)(aHalf + d + ((m * 2 + 0) << 10));
            aF[m][1] = *(const bf16x8*)(aHalf + d + ((m * 2 + 1) << 10));
        }
#pragma unroll
        for (int n = 0; n < 2; ++n) {
            b0[n][0] = *(const bf16x8*)(bHalf + d + ((n * 2 + 0) << 10));
            b0[n][1] = *(const bf16x8*)(bHalf + d + ((n * 2 + 1) << 10));
        }
        asm volatile("s_waitcnt lgkmcnt(8)" ::: "memory");
        STAGE(q + 1, 2);
        __builtin_amdgcn_s_barrier();
        asm volatile("s_waitcnt lgkmcnt(0)" ::: "memory");
        __builtin_amdgcn_sched_barrier(0);
        __builtin_amdgcn_s_setprio(1);
        MFMA_Q(0, b0);
        __builtin_amdgcn_s_setprio(0);
        __builtin_amdgcn_s_barrier();
        // -- Phase 2: read A-mh1; stage B-h1(q+1); MFMA (mh1, nh0)
#pragma unroll
        for (int m = 4; m < 8; ++m) {
            aF[m][0] = *(const bf16x8*)(aHalf + d + ((m * 2 + 0) << 10));
            aF[m][1] = *(const bf16x8*)(aHalf + d + ((m * 2 + 1) << 10));
        }
        STAGE(q + 1, 3);
        __builtin_amdgcn_s_barrier();
        asm volatile("s_waitcnt lgkmcnt(0)" ::: "memory");
        __builtin_amdgcn_sched_barrier(0);
        __builtin_amdgcn_s_setprio(1);
        MFMA_Q(4, b0);
        __builtin_amdgcn_s_setprio(0);
        __builtin_amdgcn_s_barrier();
        // -- Phase 3: read B-nh1; stage A-h0(q+2); MFMA (mh1, nh1)
#pragma unroll
        for (int n = 0; n < 2; ++n) {
            b1[n][0] = *(const bf16x8*)(bHalf + d + (((n + 2) * 2 + 0) << 10));
            b1[n][1] = *(const bf16x8*)(bHalf + d + (((n + 2) * 2 + 1) << 10));
        }
        STAGE(q + 2, 0);
        __builtin_amdgcn_s_barrier();
        asm volatile("s_waitcnt lgkmcnt(0)" ::: "memory");
        __builtin_amdgcn_sched_barrier(0);
        __builtin_amdgcn_s_setprio(1);
        MFMA_Q(4, b1);
        __builtin_amdgcn_s_setprio(0);
        __builtin_amdgcn_s_barrier();
        // -- Phase 4: stage A-h1(q+2); MFMA (mh0, nh1); counted vmcnt gate
        STAGE(q + 2, 1);
        __builtin_amdgcn_s_barrier();
        __builtin_amdgcn_s_setprio(1);
        MFMA_Q(0, b1);
        __builtin_amdgcn_s_setprio(0);
        asm volatile("s_waitcnt vmcnt(4)" ::: "memory");   // tile q+1 fully resident
        __builtin_amdgcn_s_barrier();
    }
#undef MFMA_Q

    // ---- fused epilogue: per-(row, colblock) LSE partials; alias smem ----
    __syncthreads();
    float (*part)[4][3] = (float(*)[4][3])smem;   // [256 rows][4 wc][max,sum,pick]

    // C/D layout: col = lane&15 (lr), row = kh*4 + reg j
#pragma unroll
    for (int m = 0; m < 8; ++m) {
#pragma unroll
        for (int j = 0; j < 4; ++j) {
            const int row_l = wr * 128 + m * 16 + kh * 4 + j;
            const int grow = rowBase + row_l;
            const float xs = x_sq[grow];
            const int yr = y[grow];
            float v[4];
            float vmax = -3.4e38f, pick = -1.f;
#pragma unroll
            for (int n = 0; n < 4; ++n) {
                const int col = colBase + wc * 64 + n * 16 + lr;
                const float cr = acc[m][n][j];
                const float sq = fmaxf(xs - 2.f * cr + mu_sq[col], 0.f) * 0.5f;
                const float dd = sqrtf(sq);
                const float adj = (col == yr) ? 1.5f * dd : dd;
                if (col == yr) pick = adj;
                v[n] = (col < C) ? -adj : -1e30f;
                vmax = fmaxf(vmax, v[n]);
            }
            for (int off = 1; off <= 8; off <<= 1)
                vmax = fmaxf(vmax, __shfl_xor(vmax, off, 64));
            float s = 0.f;
#pragma unroll
            for (int n = 0; n < 4; ++n) s += expf(v[n] - vmax);
            for (int off = 1; off <= 8; off <<= 1) s += __shfl_xor(s, off, 64);
            for (int off = 1; off <= 8; off <<= 1)
                pick = fmaxf(pick, __shfl_xor(pick, off, 64));
            if (lr == 0) {
                part[row_l][wc][0] = vmax;
                part[row_l][wc][1] = s;
                part[row_l][wc][2] = pick;
            }
        }
    }
    __syncthreads();
    if (t < 256) {
        float Mx = part[t][0][0], S = 0.f, pk = part[t][0][2];
#pragma unroll
        for (int b = 1; b < 4; ++b) Mx = fmaxf(Mx, part[t][b][0]);
#pragma unroll
        for (int b = 0; b < 4; ++b) {
            S += part[t][b][1] * expf(part[t][b][0] - Mx);
            pk = fmaxf(pk, part[t][b][2]);
        }
        const size_t o = (size_t)(rowBase + t) * NCB + blockIdx.y;
        pM[o] = Mx; pS[o] = S; pP[o] = pk;
    }
}

// ---- pass 3: merge colblock partials -> per-row loss -> per-block sum ----
__global__ __launch_bounds__(256) void loss_combine_kernel(
        const float* __restrict__ pM, const float* __restrict__ pS,
        const float* __restrict__ pP, float* __restrict__ bsum, int NCB) {
    const int t = threadIdx.x;
    const int row = blockIdx.x * 256 + t;
    float Mx = -3.4e38f;
    for (int b = 0; b < NCB; ++b) Mx = fmaxf(Mx, pM[(size_t)row * NCB + b]);
    float S = 0.f, pick = -1.f;
    for (int b = 0; b < NCB; ++b) {
        S += pS[(size_t)row * NCB + b] * expf(pM[(size_t)row * NCB + b] - Mx);
        pick = fmaxf(pick, pP[(size_t)row * NCB + b]);
    }
    float loss = pick + logf(S) + Mx;
    for (int off = 32; off; off >>= 1) loss += __shfl_down(loss, off, 64);
    __shared__ float sb[4];
    if ((t & 63) == 0) sb[t >> 6] = loss;
    __syncthreads();
    if (t == 0) bsum[blockIdx.x] = sb[0] + sb[1] + sb[2] + sb[3];
}

__global__ __launch_bounds__(64) void final_mean_kernel(
        const float* __restrict__ bsum, float* __restrict__ out, int nb, int N) {
    float a = 0.f;
    for (int i = threadIdx.x; i < nb; i += 64) a += bsum[i];
    for (int off = 32; off; off >>= 1) a += __shfl_down(a, off, 64);
    if (threadIdx.x == 0) out[0] = a / (float)N;
}

extern "C" void kernel_launch(void* const* d_in, const int* in_sizes, int n_in,
                              void* d_out, int out_size, void* d_ws, size_t ws_size,
                              hipStream_t stream) {
    const float* x  = (const float*)d_in[0];
    const int*   y  = (const int*)d_in[1];
    const float* mu = (const float*)d_in[2];

    const int N = in_sizes[1];                 // 16384
    const int D = in_sizes[0] / N;             // 2048
    const int C = in_sizes[2] / D;             // 1000
    const int Cpad = ((C + 255) / 256) * 256;  // 1024
    const int NCB = Cpad / BN;                 // 4 column blocks
    const int NRB = N / 256;                   // 64 row blocks

    char* ws = (char*)d_ws;
    unsigned short* x16  = (unsigned short*)ws; ws += (size_t)N * D * 2;      // 67.1 MB
    unsigned short* mu16 = (unsigned short*)ws; ws += (size_t)Cpad * D * 2;   //  4.2 MB
    float* x_sq  = (float*)ws;                  ws += (size_t)N * 4;
    float* mu_sq = (float*)ws;                  ws += (size_t)Cpad * 4;
    float* pM    = (float*)ws;                  ws += (size_t)N * NCB * 4;
    float* pS    = (float*)ws;                  ws += (size_t)N * NCB * 4;
    float* pP    = (float*)ws;                  ws += (size_t)N * NCB * 4;
    float* bsum  = (float*)ws;                  ws += (size_t)NRB * 4;

    convert_x_kernel<<<N, 256, 0, stream>>>(x, x16, x_sq, D);
    convert_mu_kernel<<<Cpad, 256, 0, stream>>>(mu, mu16, mu_sq, D, C);
    gemm_fused_kernel<<<dim3(N / BM, Cpad / BN), 512, 0, stream>>>(
        x16, mu16, x_sq, mu_sq, y, pM, pS, pP, D, C, NCB);
    loss_combine_kernel<<<NRB, 256, 0, stream>>>(pM, pS, pP, bsum, NCB);
    final_mean_kernel<<<1, 64, 0, stream>>>(bsum, d_out ? (float*)d_out : nullptr, NRB, N);
}

// Round 6
// 89.776 us; speedup vs baseline: 1.5057x; 1.3212x over previous
//
#include <hip/hip_runtime.h>

typedef float f32x4  __attribute__((ext_vector_type(4)));
typedef int   i32x4  __attribute__((ext_vector_type(4)));
typedef int   i32x8  __attribute__((ext_vector_type(8)));

__device__ inline void gload_lds16(const void* g, void* l) {
    __builtin_amdgcn_global_load_lds((const __attribute__((address_space(1))) void*)g,
                                     (__attribute__((address_space(3))) void*)l,
                                     16, 0, 0);
}

// pack 4 f32 -> 4 fp8 e4m3 (OCP, RNE in HW)
__device__ inline unsigned int pack_fp8x4(float a, float b, float c, float d) {
    int p = __builtin_amdgcn_cvt_pk_fp8_f32(a, b, 0, false);   // low 16 bits
    p = __builtin_amdgcn_cvt_pk_fp8_f32(c, d, p, true);        // high 16 bits
    return (unsigned int)p;
}

// ---- pass 1a: x f32 -> fp8, plus per-row sum of squares (f32, exact) ----
__global__ __launch_bounds__(256) void convert_x_kernel(
        const float* __restrict__ x, unsigned int* __restrict__ x8,
        float* __restrict__ x_sq, int D) {
    const int n = blockIdx.x;
    const int t = threadIdx.x;
    const float* xr = x + (size_t)n * D;
    unsigned int* xo = x8 + (size_t)n * (D / 4);
    float acc = 0.f;
    for (int p = 0; p < D / 1024; ++p) {
        const int col = p * 1024 + t * 4;
        float4 v = *(const float4*)(xr + col);
        acc += v.x * v.x + v.y * v.y + v.z * v.z + v.w * v.w;
        xo[col / 4] = pack_fp8x4(v.x, v.y, v.z, v.w);
    }
    for (int off = 32; off; off >>= 1) acc += __shfl_down(acc, off, 64);
    __shared__ float sbuf[4];
    if ((t & 63) == 0) sbuf[t >> 6] = acc;
    __syncthreads();
    if (t == 0) x_sq[n] = sbuf[0] + sbuf[1] + sbuf[2] + sbuf[3];
}

// ---- pass 1b: mu f32 -> fp8 (zero-padded to Cpad rows), plus mu_sq ----
__global__ __launch_bounds__(256) void convert_mu_kernel(
        const float* __restrict__ mu, unsigned int* __restrict__ mu8,
        float* __restrict__ mu_sq, int D, int C) {
    const int c = blockIdx.x;
    const int t = threadIdx.x;
    unsigned int* mo = mu8 + (size_t)c * (D / 4);
    if (c >= C) {
        for (int p = 0; p < D / 1024; ++p) mo[(p * 1024 + t * 4) / 4] = 0u;
        if (t == 0) mu_sq[c] = 0.f;
        return;
    }
    const float* mr = mu + (size_t)c * D;
    float acc = 0.f;
    for (int p = 0; p < D / 1024; ++p) {
        const int col = p * 1024 + t * 4;
        float4 v = *(const float4*)(mr + col);
        acc += v.x * v.x + v.y * v.y + v.z * v.z + v.w * v.w;
        mo[col / 4] = pack_fp8x4(v.x, v.y, v.z, v.w);
    }
    for (int off = 32; off; off >>= 1) acc += __shfl_down(acc, off, 64);
    __shared__ float sbuf[4];
    if ((t & 63) == 0) sbuf[t >> 6] = acc;
    __syncthreads();
    if (t == 0) mu_sq[c] = sbuf[0] + sbuf[1] + sbuf[2] + sbuf[3];
}

// ---- pass 2: 256x256x128 fp8 GEMM (mfma_scale 16x16x128, unit scales) ----
// LDS buffer b (64KB @ b*65536): A [256 rows][128 B] @0, B [256 rows][128 B] @32K.
// Swizzle: 16B-chunk slot ch holds logical chunk ch ^ (row&7)  (involution).
#define BM 256
#define BN 256
#define BK 128

__global__ __launch_bounds__(512, 2) void gemm_fused_kernel(
        const unsigned char* __restrict__ A,   // [M][K] fp8
        const unsigned char* __restrict__ B,   // [Cpad][K] fp8
        const float* __restrict__ x_sq, const float* __restrict__ mu_sq,
        const int* __restrict__ y,
        float* __restrict__ pM, float* __restrict__ pS, float* __restrict__ pP,
        int K, int C, int NCB) {
    __shared__ __align__(16) char smem[131072];   // 2 x 64KB

    const int t  = threadIdx.x;
    const int l  = t & 63, w = t >> 6;
    const int wr = w >> 2, wc = w & 3;            // 2M x 4N waves, 128x64 each
    const int lr = l & 15, kh = l >> 4;
    const int rowBase = blockIdx.x * BM;
    const int colBase = blockIdx.y * BN;
    const int nt = K / BK;                        // 16 K-tiles

    // ---- staging: linear LDS dest (t*16), pre-swizzled global source ----
    // LDS slot: row = r*64 + (t>>3), phys chunk = t&7  -> logical chunk ^ (row&7)
    const int lc = (t & 7) ^ ((t >> 3) & 7);
    const unsigned char* gA = A + (size_t)(rowBase + (t >> 3)) * K + lc * 16;
    const unsigned char* gB = B + (size_t)(colBase + (t >> 3)) * K + lc * 16;

    auto STAGE = [&](int q) {
        const int qc = (q < nt) ? q : nt - 1;     // tail: harmless rewrite
        char* dst = smem + (q & 1) * 65536 + t * 16;
        const unsigned char* ga = gA + (size_t)qc * BK;
        const unsigned char* gb = gB + (size_t)qc * BK;
#pragma unroll
        for (int r = 0; r < 4; ++r)
            gload_lds16(ga + (size_t)r * 64 * K, dst + r * 8192);
#pragma unroll
        for (int r = 0; r < 4; ++r)
            gload_lds16(gb + (size_t)r * 64 * K, dst + 32768 + r * 8192);
    };

    // ---- read side: frag row stride 128B = exactly 32 banks; swizzle fixes ----
    const int ch0 = ((kh * 2) ^ (lr & 7)) << 4;       // logical chunk 2kh
    const int ch1 = ((kh * 2 + 1) ^ (lr & 7)) << 4;   // logical chunk 2kh+1
    const int aRow = (wr * 128 + lr) * 128;
    const int bRow = 32768 + (wc * 64 + lr) * 128;

    f32x4 acc[8][4];
#pragma unroll
    for (int m = 0; m < 8; ++m)
#pragma unroll
        for (int n = 0; n < 4; ++n) acc[m][n] = (f32x4){0.f, 0.f, 0.f, 0.f};

    STAGE(0);
    asm volatile("s_waitcnt vmcnt(0)" ::: "memory");
    __builtin_amdgcn_s_barrier();

    const int SC = 0x7f7f7f7f;                    // e8m0 = 127 -> scale 1.0

#pragma unroll 1
    for (int q = 0; q < nt; ++q) {
        STAGE(q + 1);                              // into other buffer
        const char* buf = smem + (q & 1) * 65536;
        i32x8 aF[8], bF[4];
#pragma unroll
        for (int m = 0; m < 8; ++m) {
            i32x4 a0 = *(const i32x4*)(buf + aRow + m * 2048 + ch0);
            i32x4 a1 = *(const i32x4*)(buf + aRow + m * 2048 + ch1);
            aF[m] = __builtin_shufflevector(a0, a1, 0, 1, 2, 3, 4, 5, 6, 7);
        }
#pragma unroll
        for (int n = 0; n < 4; ++n) {
            i32x4 b0 = *(const i32x4*)(buf + bRow + n * 2048 + ch0);
            i32x4 b1 = *(const i32x4*)(buf + bRow + n * 2048 + ch1);
            bF[n] = __builtin_shufflevector(b0, b1, 0, 1, 2, 3, 4, 5, 6, 7);
        }
        asm volatile("s_waitcnt lgkmcnt(0)" ::: "memory");
        __builtin_amdgcn_sched_barrier(0);
        __builtin_amdgcn_s_setprio(1);
#pragma unroll
        for (int m = 0; m < 8; ++m)
#pragma unroll
            for (int n = 0; n < 4; ++n)
                acc[m][n] = __builtin_amdgcn_mfma_scale_f32_16x16x128_f8f6f4(
                    aF[m], bF[n], acc[m][n], 0, 0, 0, SC, 0, SC);
        __builtin_amdgcn_s_setprio(0);
        asm volatile("s_waitcnt vmcnt(0)" ::: "memory");   // next tile resident
        __builtin_amdgcn_s_barrier();
    }

    // ---- fused epilogue: per-(row, colblock) LSE partials; alias smem ----
    __syncthreads();
    float (*part)[4][3] = (float(*)[4][3])smem;   // [256 rows][4 wc][max,sum,pick]

    // C/D layout: col = lane&15 (lr), row = kh*4 + reg j
#pragma unroll
    for (int m = 0; m < 8; ++m) {
#pragma unroll
        for (int j = 0; j < 4; ++j) {
            const int row_l = wr * 128 + m * 16 + kh * 4 + j;
            const int grow = rowBase + row_l;
            const float xs = x_sq[grow];
            const int yr = y[grow];
            float v[4];
            float vmax = -3.4e38f, pick = -1.f;
#pragma unroll
            for (int n = 0; n < 4; ++n) {
                const int col = colBase + wc * 64 + n * 16 + lr;
                const float cr = acc[m][n][j];
                const float sq = fmaxf(xs - 2.f * cr + mu_sq[col], 0.f) * 0.5f;
                const float dd = sqrtf(sq);
                const float adj = (col == yr) ? 1.5f * dd : dd;
                if (col == yr) pick = adj;
                v[n] = (col < C) ? -adj : -1e30f;
                vmax = fmaxf(vmax, v[n]);
            }
            for (int off = 1; off <= 8; off <<= 1)
                vmax = fmaxf(vmax, __shfl_xor(vmax, off, 64));
            float s = 0.f;
#pragma unroll
            for (int n = 0; n < 4; ++n) s += expf(v[n] - vmax);
            for (int off = 1; off <= 8; off <<= 1) s += __shfl_xor(s, off, 64);
            for (int off = 1; off <= 8; off <<= 1)
                pick = fmaxf(pick, __shfl_xor(pick, off, 64));
            if (lr == 0) {
                part[row_l][wc][0] = vmax;
                part[row_l][wc][1] = s;
                part[row_l][wc][2] = pick;
            }
        }
    }
    __syncthreads();
    if (t < 256) {
        float Mx = part[t][0][0], S = 0.f, pk = part[t][0][2];
#pragma unroll
        for (int b = 1; b < 4; ++b) Mx = fmaxf(Mx, part[t][b][0]);
#pragma unroll
        for (int b = 0; b < 4; ++b) {
            S += part[t][b][1] * expf(part[t][b][0] - Mx);
            pk = fmaxf(pk, part[t][b][2]);
        }
        const size_t o = (size_t)(rowBase + t) * NCB + blockIdx.y;
        pM[o] = Mx; pS[o] = S; pP[o] = pk;
    }
}

// ---- pass 3: merge colblock partials -> per-row loss -> per-block sum ----
__global__ __launch_bounds__(256) void loss_combine_kernel(
        const float* __restrict__ pM, const float* __restrict__ pS,
        const float* __restrict__ pP, float* __restrict__ bsum, int NCB) {
    const int t = threadIdx.x;
    const int row = blockIdx.x * 256 + t;
    float Mx = -3.4e38f;
    for (int b = 0; b < NCB; ++b) Mx = fmaxf(Mx, pM[(size_t)row * NCB + b]);
    float S = 0.f, pick = -1.f;
    for (int b = 0; b < NCB; ++b) {
        S += pS[(size_t)row * NCB + b] * expf(pM[(size_t)row * NCB + b] - Mx);
        pick = fmaxf(pick, pP[(size_t)row * NCB + b]);
    }
    float loss = pick + logf(S) + Mx;
    for (int off = 32; off; off >>= 1) loss += __shfl_down(loss, off, 64);
    __shared__ float sb[4];
    if ((t & 63) == 0) sb[t >> 6] = loss;
    __syncthreads();
    if (t == 0) bsum[blockIdx.x] = sb[0] + sb[1] + sb[2] + sb[3];
}

__global__ __launch_bounds__(64) void final_mean_kernel(
        const float* __restrict__ bsum, float* __restrict__ out, int nb, int N) {
    float a = 0.f;
    for (int i = threadIdx.x; i < nb; i += 64) a += bsum[i];
    for (int off = 32; off; off >>= 1) a += __shfl_down(a, off, 64);
    if (threadIdx.x == 0) out[0] = a / (float)N;
}

extern "C" void kernel_launch(void* const* d_in, const int* in_sizes, int n_in,
                              void* d_out, int out_size, void* d_ws, size_t ws_size,
                              hipStream_t stream) {
    const float* x  = (const float*)d_in[0];
    const int*   y  = (const int*)d_in[1];
    const float* mu = (const float*)d_in[2];

    const int N = in_sizes[1];                 // 16384
    const int D = in_sizes[0] / N;             // 2048
    const int C = in_sizes[2] / D;             // 1000
    const int Cpad = ((C + 255) / 256) * 256;  // 1024
    const int NCB = Cpad / BN;                 // 4 column blocks
    const int NRB = N / 256;                   // 64 row blocks

    char* ws = (char*)d_ws;
    unsigned char* x8  = (unsigned char*)ws;  ws += (size_t)N * D;        // 33.6 MB
    unsigned char* mu8 = (unsigned char*)ws;  ws += (size_t)Cpad * D;     //  2.1 MB
    float* x_sq  = (float*)ws;                ws += (size_t)N * 4;
    float* mu_sq = (float*)ws;                ws += (size_t)Cpad * 4;
    float* pM    = (float*)ws;                ws += (size_t)N * NCB * 4;
    float* pS    = (float*)ws;                ws += (size_t)N * NCB * 4;
    float* pP    = (float*)ws;                ws += (size_t)N * NCB * 4;
    float* bsum  = (float*)ws;                ws += (size_t)NRB * 4;

    convert_x_kernel<<<N, 256, 0, stream>>>(x, (unsigned int*)x8, x_sq, D);
    convert_mu_kernel<<<Cpad, 256, 0, stream>>>(mu, (unsigned int*)mu8, mu_sq, D, C);
    gemm_fused_kernel<<<dim3(N / BM, Cpad / BN), 512, 0, stream>>>(
        x8, mu8, x_sq, mu_sq, y, pM, pS, pP, D, C, NCB);
    loss_combine_kernel<<<NRB, 256, 0, stream>>>(pM, pS, pP, bsum, NCB);
    final_mean_kernel<<<1, 64, 0, stream>>>(bsum, d_out ? (float*)d_out : nullptr, NRB, N);
}

// Round 7
// 75.036 us; speedup vs baseline: 1.8015x; 1.1964x over previous
//
#include <hip/hip_runtime.h>

typedef float f32x4  __attribute__((ext_vector_type(4)));
typedef int   i32x4  __attribute__((ext_vector_type(4)));
typedef int   i32x8  __attribute__((ext_vector_type(8)));

__device__ inline void gload_lds16(const void* g, void* l) {
    __builtin_amdgcn_global_load_lds((const __attribute__((address_space(1))) void*)g,
                                     (__attribute__((address_space(3))) void*)l,
                                     16, 0, 0);
}

// f32 -> fp4 e2m1 (RNE via threshold ladder): values {0,.5,1,1.5,2,3,4,6}
__device__ inline unsigned int enc_fp4(float v) {
    float a = fabsf(v);
    unsigned int c = (unsigned int)(a > 0.25f) + (a > 0.75f) + (a > 1.25f) +
                     (a > 1.75f) + (a > 2.5f)  + (a > 3.5f)  + (a > 5.0f);
    return c | ((v < 0.f) ? 8u : 0u);
}

// ---- pass 1: {x, mu} f32 -> fp4, plus exact f32 sum-of-squares per row ----
// grid = N + Cpad blocks; 256 threads x 8 elems = 2048 = D
__global__ __launch_bounds__(256) void convert_kernel(
        const float* __restrict__ x, const float* __restrict__ mu,
        unsigned int* __restrict__ x4, unsigned int* __restrict__ mu4,
        float* __restrict__ x_sq, float* __restrict__ mu_sq,
        int D, int N, int C, int Cpad) {
    const int bid = blockIdx.x;
    const int t = threadIdx.x;
    const bool isX = bid < N;
    const int r = isX ? bid : bid - N;           // row within x or mu

    unsigned int* out = (isX ? x4 : mu4) + (size_t)r * (D / 8) + t;
    if (!isX && r >= C) {                        // pad rows: fp4 zeros
        *out = 0u;
        if (t == 0) mu_sq[r] = 0.f;
        return;
    }
    const float* src = (isX ? x + (size_t)r * D : mu + (size_t)r * D) + t * 8;
    float4 v0 = *(const float4*)(src);
    float4 v1 = *(const float4*)(src + 4);
    float acc = v0.x * v0.x + v0.y * v0.y + v0.z * v0.z + v0.w * v0.w
              + v1.x * v1.x + v1.y * v1.y + v1.z * v1.z + v1.w * v1.w;
    unsigned int p = enc_fp4(v0.x) | (enc_fp4(v0.y) << 4) | (enc_fp4(v0.z) << 8)
                   | (enc_fp4(v0.w) << 12) | (enc_fp4(v1.x) << 16)
                   | (enc_fp4(v1.y) << 20) | (enc_fp4(v1.z) << 24)
                   | (enc_fp4(v1.w) << 28);
    *out = p;

    for (int off = 32; off; off >>= 1) acc += __shfl_down(acc, off, 64);
    __shared__ float sbuf[4];
    if ((t & 63) == 0) sbuf[t >> 6] = acc;
    __syncthreads();
    if (t == 0) {
        float s = sbuf[0] + sbuf[1] + sbuf[2] + sbuf[3];
        if (isX) x_sq[r] = s; else mu_sq[r] = s;
    }
}

// ---- pass 2: 256x256x(K) fp4 GEMM, BK=256 elems (128 B rows), fused LSE ----
// LDS buffer b (64KB @ b*65536): A [256 rows][128 B] @0, B [256 rows][128 B] @32K.
// Swizzle: 16B-chunk slot ch holds logical chunk ch ^ (row&7)  (involution).
// One 16B chunk = 32 fp4 elems = one MX block = one lane-fragment of K=128 MFMA.
#define BM 256
#define BN 256
#define BKE 256   /* K elems per tile = 128 bytes */

__global__ __launch_bounds__(512, 2) void gemm_fused_kernel(
        const unsigned char* __restrict__ A,   // [M][Kb] fp4 (Kb bytes/row)
        const unsigned char* __restrict__ B,   // [Cpad][Kb] fp4
        const float* __restrict__ x_sq, const float* __restrict__ mu_sq,
        const int* __restrict__ y,
        float* __restrict__ pM, float* __restrict__ pS, float* __restrict__ pP,
        int Kb, int C, int NCB) {
    __shared__ __align__(16) char smem[131072];   // 2 x 64KB

    const int t  = threadIdx.x;
    const int l  = t & 63, w = t >> 6;
    const int wr = w >> 2, wc = w & 3;            // 2M x 4N waves, 128x64 each
    const int lr = l & 15, kh = l >> 4;
    const int rowBase = blockIdx.x * BM;
    const int colBase = blockIdx.y * BN;
    const int nt = (Kb * 2) / BKE;                // 8 K-tiles

    // ---- staging: linear LDS dest (t*16), pre-swizzled global source ----
    const int lc = (t & 7) ^ ((t >> 3) & 7);      // logical chunk this slot holds
    const unsigned char* gA = A + (size_t)(rowBase + (t >> 3)) * Kb + lc * 16;
    const unsigned char* gB = B + (size_t)(colBase + (t >> 3)) * Kb + lc * 16;

    auto STAGE = [&](int q) {
        const int qc = (q < nt) ? q : nt - 1;     // tail: harmless rewrite
        char* dst = smem + (q & 1) * 65536 + t * 16;
        const unsigned char* ga = gA + (size_t)qc * 128;
        const unsigned char* gb = gB + (size_t)qc * 128;
#pragma unroll
        for (int r = 0; r < 4; ++r)
            gload_lds16(ga + (size_t)r * 64 * Kb, dst + r * 8192);
#pragma unroll
        for (int r = 0; r < 4; ++r)
            gload_lds16(gb + (size_t)r * 64 * Kb, dst + 32768 + r * 8192);
    };

    const int aRow = (wr * 128 + lr) * 128;
    const int bRow = 32768 + (wc * 64 + lr) * 128;
    const int swz = (lr & 7);

    f32x4 acc[8][4];
#pragma unroll
    for (int m = 0; m < 8; ++m)
#pragma unroll
        for (int n = 0; n < 4; ++n) acc[m][n] = (f32x4){0.f, 0.f, 0.f, 0.f};

    STAGE(0);
    asm volatile("s_waitcnt vmcnt(0)" ::: "memory");
    __builtin_amdgcn_s_barrier();

    const int SC = 0x7f7f7f7f;                    // e8m0 = 127 -> scale 1.0

#pragma unroll 1
    for (int q = 0; q < nt; ++q) {
        STAGE(q + 1);                              // into other buffer
        const char* buf = smem + (q & 1) * 65536;
#pragma unroll
        for (int s = 0; s < 2; ++s) {              // two K=128 sub-tiles
            const int ch = ((s * 4 + kh) ^ swz) << 4;
            i32x4 aF[8], bF[4];
#pragma unroll
            for (int m = 0; m < 8; ++m)
                aF[m] = *(const i32x4*)(buf + aRow + m * 2048 + ch);
#pragma unroll
            for (int n = 0; n < 4; ++n)
                bF[n] = *(const i32x4*)(buf + bRow + n * 2048 + ch);
            asm volatile("s_waitcnt lgkmcnt(0)" ::: "memory");
            __builtin_amdgcn_sched_barrier(0);
            __builtin_amdgcn_s_setprio(1);
#pragma unroll
            for (int m = 0; m < 8; ++m) {
                i32x8 a8 = __builtin_shufflevector(aF[m], aF[m], 0, 1, 2, 3, 0, 1, 2, 3);
#pragma unroll
                for (int n = 0; n < 4; ++n) {
                    i32x8 b8 = __builtin_shufflevector(bF[n], bF[n], 0, 1, 2, 3, 0, 1, 2, 3);
                    acc[m][n] = __builtin_amdgcn_mfma_scale_f32_16x16x128_f8f6f4(
                        a8, b8, acc[m][n], 4 /*fp4*/, 4 /*fp4*/, 0, SC, 0, SC);
                }
            }
            __builtin_amdgcn_s_setprio(0);
        }
        asm volatile("s_waitcnt vmcnt(0)" ::: "memory");   // next tile resident
        __builtin_amdgcn_s_barrier();
    }

    // ---- fused epilogue: per-(row, colblock) LSE partials; alias smem ----
    __syncthreads();
    float (*part)[4][3] = (float(*)[4][3])smem;   // [256 rows][4 wc][max,sum,pick]

    // C/D layout: col = lane&15 (lr), row = kh*4 + reg j
#pragma unroll
    for (int m = 0; m < 8; ++m) {
#pragma unroll
        for (int j = 0; j < 4; ++j) {
            const int row_l = wr * 128 + m * 16 + kh * 4 + j;
            const int grow = rowBase + row_l;
            const float xs = x_sq[grow];
            const int yr = y[grow];
            float v[4];
            float vmax = -3.4e38f, pick = -1.f;
#pragma unroll
            for (int n = 0; n < 4; ++n) {
                const int col = colBase + wc * 64 + n * 16 + lr;
                const float cr = acc[m][n][j];
                const float sq = fmaxf(xs - 2.f * cr + mu_sq[col], 0.f) * 0.5f;
                const float dd = sqrtf(sq);
                const float adj = (col == yr) ? 1.5f * dd : dd;
                if (col == yr) pick = adj;
                v[n] = (col < C) ? -adj : -1e30f;
                vmax = fmaxf(vmax, v[n]);
            }
            for (int off = 1; off <= 8; off <<= 1)
                vmax = fmaxf(vmax, __shfl_xor(vmax, off, 64));
            float s = 0.f;
#pragma unroll
            for (int n = 0; n < 4; ++n) s += expf(v[n] - vmax);
            for (int off = 1; off <= 8; off <<= 1) s += __shfl_xor(s, off, 64);
            for (int off = 1; off <= 8; off <<= 1)
                pick = fmaxf(pick, __shfl_xor(pick, off, 64));
            if (lr == 0) {
                part[row_l][wc][0] = vmax;
                part[row_l][wc][1] = s;
                part[row_l][wc][2] = pick;
            }
        }
    }
    __syncthreads();
    if (t < 256) {
        float Mx = part[t][0][0], S = 0.f, pk = part[t][0][2];
#pragma unroll
        for (int b = 1; b < 4; ++b) Mx = fmaxf(Mx, part[t][b][0]);
#pragma unroll
        for (int b = 0; b < 4; ++b) {
            S += part[t][b][1] * expf(part[t][b][0] - Mx);
            pk = fmaxf(pk, part[t][b][2]);
        }
        const size_t o = (size_t)(rowBase + t) * NCB + blockIdx.y;
        pM[o] = Mx; pS[o] = S; pP[o] = pk;
    }
}

// ---- pass 3: merge colblock partials -> per-row loss -> per-block sum ----
__global__ __launch_bounds__(256) void loss_combine_kernel(
        const float* __restrict__ pM, const float* __restrict__ pS,
        const float* __restrict__ pP, float* __restrict__ bsum, int NCB) {
    const int t = threadIdx.x;
    const int row = blockIdx.x * 256 + t;
    float Mx = -3.4e38f;
    for (int b = 0; b < NCB; ++b) Mx = fmaxf(Mx, pM[(size_t)row * NCB + b]);
    float S = 0.f, pick = -1.f;
    for (int b = 0; b < NCB; ++b) {
        S += pS[(size_t)row * NCB + b] * expf(pM[(size_t)row * NCB + b] - Mx);
        pick = fmaxf(pick, pP[(size_t)row * NCB + b]);
    }
    float loss = pick + logf(S) + Mx;
    for (int off = 32; off; off >>= 1) loss += __shfl_down(loss, off, 64);
    __shared__ float sb[4];
    if ((t & 63) == 0) sb[t >> 6] = loss;
    __syncthreads();
    if (t == 0) bsum[blockIdx.x] = sb[0] + sb[1] + sb[2] + sb[3];
}

__global__ __launch_bounds__(64) void final_mean_kernel(
        const float* __restrict__ bsum, float* __restrict__ out, int nb, int N) {
    float a = 0.f;
    for (int i = threadIdx.x; i < nb; i += 64) a += bsum[i];
    for (int off = 32; off; off >>= 1) a += __shfl_down(a, off, 64);
    if (threadIdx.x == 0) out[0] = a / (float)N;
}

extern "C" void kernel_launch(void* const* d_in, const int* in_sizes, int n_in,
                              void* d_out, int out_size, void* d_ws, size_t ws_size,
                              hipStream_t stream) {
    const float* x  = (const float*)d_in[0];
    const int*   y  = (const int*)d_in[1];
    const float* mu = (const float*)d_in[2];

    const int N = in_sizes[1];                 // 16384
    const int D = in_sizes[0] / N;             // 2048
    const int C = in_sizes[2] / D;             // 1000
    const int Cpad = ((C + 255) / 256) * 256;  // 1024
    const int NCB = Cpad / BN;                 // 4 column blocks
    const int NRB = N / 256;                   // 64 row blocks
    const int Kb = D / 2;                      // fp4 bytes per row (1024)

    char* ws = (char*)d_ws;
    unsigned char* x4  = (unsigned char*)ws;  ws += (size_t)N * Kb;       // 16.8 MB
    unsigned char* mu4 = (unsigned char*)ws;  ws += (size_t)Cpad * Kb;    //  1.0 MB
    float* x_sq  = (float*)ws;                ws += (size_t)N * 4;
    float* mu_sq = (float*)ws;                ws += (size_t)Cpad * 4;
    float* pM    = (float*)ws;                ws += (size_t)N * NCB * 4;
    float* pS    = (float*)ws;                ws += (size_t)N * NCB * 4;
    float* pP    = (float*)ws;                ws += (size_t)N * NCB * 4;
    float* bsum  = (float*)ws;                ws += (size_t)NRB * 4;

    convert_kernel<<<N + Cpad, 256, 0, stream>>>(
        x, mu, (unsigned int*)x4, (unsigned int*)mu4, x_sq, mu_sq, D, N, C, Cpad);
    gemm_fused_kernel<<<dim3(N / BM, Cpad / BN), 512, 0, stream>>>(
        x4, mu4, x_sq, mu_sq, y, pM, pS, pP, Kb, C, NCB);
    loss_combine_kernel<<<NRB, 256, 0, stream>>>(pM, pS, pP, bsum, NCB);
    final_mean_kernel<<<1, 64, 0, stream>>>(bsum, d_out ? (float*)d_out : nullptr, NRB, N);
}